// Round 1
// baseline (483.666 us; speedup 1.0000x reference)
//
#include <hip/hip_runtime.h>
#include <hip/hip_bf16.h>
#include <math.h>

typedef __bf16 bf16_t;
typedef __bf16 vbf4 __attribute__((ext_vector_type(4)));
typedef __bf16 vbf8 __attribute__((ext_vector_type(8)));
typedef float  vf4  __attribute__((ext_vector_type(4)));

// Workspace layout (bytes). Total = 207,618,048 (~198 MB)
// OFF_XB region is triple-used (stream-ordered): Xb -> Lp partials -> CtxTok
#define OFF_XB   0ull                 // Xb bf16 [32768][768] = 50331648
                                      //  = Lp f32 [16][12][256][256] (logits partials)
                                      //  = CtxTok bf16 [32768][768]
#define OFF_Q    50331648ull          // Qh bf16 [12][256][8192]
#define OFF_K    100663296ull         // Kh bf16 [12][256][8192]
#define OFF_VT   150994944ull         // Vt bf16 [12][8192][256]
#define OFF_P    201326592ull         // P  bf16 [12][256][256]
#define OFF_WQ   202899456ull         // WqT bf16 [768][768] (pre-scaled)
#define OFF_WK   204079104ull
#define OFF_WV   205258752ull
#define OFF_WO   206438400ull

// ---------------------------------------------------------------------------
// Staging: ROWS x 64 bf16 tile via global_load_lds width=16, XOR-swizzled:
// LDS[r][chunk j] holds global chunk (j ^ (r&7)).  (256-thread version, logits)
// ---------------------------------------------------------------------------
template <int ROWS>
__device__ __forceinline__ void stage_tile(const bf16_t* __restrict__ g,
                                           int ld, int row0, int k0,
                                           bf16_t* lds, int tid) {
  const int wave = tid >> 6;
  const int lane = tid & 63;
  const int js = (lane & 7) ^ (lane >> 3);
#pragma unroll
  for (int cc = 0; cc < ROWS / 32; ++cc) {
    const int chunk = cc * 4 + wave;
    const int row = chunk * 8 + (lane >> 3);
    const bf16_t* gp = g + (size_t)(row0 + row) * ld + k0 + js * 8;
    bf16_t* lp = lds + chunk * 512 + lane * 8;
    __builtin_amdgcn_global_load_lds(
        (const __attribute__((address_space(1))) void*)gp,
        (__attribute__((address_space(3))) void*)lp, 16, 0, 0);
  }
}

// 512-thread (8-wave) half-tile stage: 128 rows x 64 cols, 2 loads/thread.
// half selects rows [half*128, half*128+128) of a 256-row tile.
__device__ __forceinline__ void stage_half(const bf16_t* __restrict__ g,
                                           int ld, int row0, int k0,
                                           bf16_t* lds, int half, int tid) {
  const int wave = tid >> 6;
  const int lane = tid & 63;
  const int js = (lane & 7) ^ (lane >> 3);
#pragma unroll
  for (int cc = 0; cc < 2; ++cc) {
    const int chunk = half * 16 + cc * 8 + wave;
    const int row = chunk * 8 + (lane >> 3);
    const bf16_t* gp = g + (size_t)(row0 + row) * ld + k0 + js * 8;
    bf16_t* lp = lds + chunk * 512 + lane * 8;
    __builtin_amdgcn_global_load_lds(
        (const __attribute__((address_space(1))) void*)gp,
        (__attribute__((address_space(3))) void*)lp, 16, 0, 0);
  }
}

__device__ __forceinline__ vbf8 lds_frag(const bf16_t* s, int rr, int ko) {
  const int c = (ko >> 3) ^ (rr & 7);
  return *(const vbf8*)&s[rr * 64 + (c << 3)];
}

// ---------------------------------------------------------------------------
// 128x128 mainloop (4 waves, 4x4 tiles/wave) — used by logits (split-K)
// ---------------------------------------------------------------------------
__device__ __forceinline__ void gemm_mainloop128(const bf16_t* __restrict__ A, int lda, int m0,
                                                 const bf16_t* __restrict__ Bt, int ldb, int n0,
                                                 int kbeg, int kend,
                                                 bf16_t* As, bf16_t* Bs,
                                                 vf4 (&acc)[4][4]) {
  const int tid = threadIdx.x;
  const int lane = tid & 63;
  const int wave = tid >> 6;
  const int wm0 = (wave >> 1) * 64;
  const int wn0 = (wave & 1) * 64;
  const int fm = lane & 15;
  const int fk = (lane >> 4) * 8;
  for (int k0 = kbeg; k0 < kend; k0 += 64) {
    stage_tile<128>(A, lda, m0, k0, As, tid);
    stage_tile<128>(Bt, ldb, n0, k0, Bs, tid);
    __syncthreads();
#pragma unroll
    for (int kk = 0; kk < 64; kk += 32) {
      vbf8 af[4], bfv[4];
#pragma unroll
      for (int mt = 0; mt < 4; ++mt) af[mt] = lds_frag(As, wm0 + mt * 16 + fm, kk + fk);
#pragma unroll
      for (int nt = 0; nt < 4; ++nt) bfv[nt] = lds_frag(Bs, wn0 + nt * 16 + fm, kk + fk);
#pragma unroll
      for (int mt = 0; mt < 4; ++mt)
#pragma unroll
        for (int nt = 0; nt < 4; ++nt)
          acc[mt][nt] = __builtin_amdgcn_mfma_f32_16x16x32_bf16(af[mt], bfv[nt],
                                                                acc[mt][nt], 0, 0, 0);
    }
    __syncthreads();
  }
}

// ---------------------------------------------------------------------------
// 256x256 pipelined mainloop. 8 waves (512 thr), wave tile 128x64 (8x4 frags).
// Double-buffered LDS (128 KiB), 4 phases/K-tile, counted vmcnt (never 0 in
// steady state), raw s_barrier, setprio around MFMA clusters.
//
// Schedule invariants (race-free by construction):
//  - B frags for the whole K-tile are register-loaded in phase 0 -> cur B
//    buffer is dead from phase 1 on; B(t+2) staged into it in phases 2-3.
//  - A(t+1) staged into the OTHER buffer (its tile t-1 reads finished last
//    iteration) in phases 0-1.
//  - End-of-tile s_waitcnt vmcnt(4): leaves only B(t+2)'s 4 loads in flight;
//    A(t+1) (and the older B(t+1)) are guaranteed landed. Barrier after.
// ---------------------------------------------------------------------------
__device__ __forceinline__ void gemm_pipe256(const bf16_t* __restrict__ A, int lda, int m0,
                                             const bf16_t* __restrict__ Bt, int ldb, int n0,
                                             int nt,
                                             bf16_t (&As)[2][256 * 64],
                                             bf16_t (&Bs)[2][256 * 64],
                                             vf4 (&acc)[8][4]) {
  const int tid = threadIdx.x;
  const int lane = tid & 63;
  const int wave = tid >> 6;
  const int aRow0 = (wave >> 2) * 128;   // WARPS_M = 2
  const int bRow0 = (wave & 3) * 64;     // WARPS_N = 4
  const int fm = lane & 15;
  const int fk = (lane >> 4) * 8;

  // prologue: A(0),B(0) -> buf0 ; B(1) -> buf1 (A(1) staged by iteration 0)
  stage_half(A, lda, m0, 0, As[0], 0, tid);
  stage_half(A, lda, m0, 0, As[0], 1, tid);
  stage_half(Bt, ldb, n0, 0, Bs[0], 0, tid);
  stage_half(Bt, ldb, n0, 0, Bs[0], 1, tid);
  if (nt > 1) {
    stage_half(Bt, ldb, n0, 64, Bs[1], 0, tid);
    stage_half(Bt, ldb, n0, 64, Bs[1], 1, tid);
    asm volatile("s_waitcnt vmcnt(4)" ::: "memory");  // A(0)+B(0) landed
  } else {
    asm volatile("s_waitcnt vmcnt(0)" ::: "memory");
  }
  __builtin_amdgcn_s_barrier();

  for (int t = 0; t < nt; ++t) {
    const int cur = t & 1;
    bf16_t* as = As[cur];
    bf16_t* bs = Bs[cur];
    bf16_t* an = As[cur ^ 1];
    vbf8 bfv[4][2];  // whole-K-tile B frags, held across phases
#pragma unroll
    for (int q = 0; q < 4; ++q) {
      vbf8 af[2][2];
#pragma unroll
      for (int m2 = 0; m2 < 2; ++m2)
#pragma unroll
        for (int kk = 0; kk < 2; ++kk)
          af[m2][kk] = lds_frag(as, aRow0 + q * 32 + m2 * 16 + fm, kk * 32 + fk);
      if (q == 0) {
#pragma unroll
        for (int bn = 0; bn < 4; ++bn)
#pragma unroll
          for (int kk = 0; kk < 2; ++kk)
            bfv[bn][kk] = lds_frag(bs, bRow0 + bn * 16 + fm, kk * 32 + fk);
      }
      if (q < 2) {
        if (t + 1 < nt) stage_half(A, lda, m0, (t + 1) * 64, an, q, tid);
      } else {
        if (t + 2 < nt) stage_half(Bt, ldb, n0, (t + 2) * 64, bs, q - 2, tid);
      }
      __builtin_amdgcn_s_barrier();
      __builtin_amdgcn_s_setprio(1);
#pragma unroll
      for (int m2 = 0; m2 < 2; ++m2)
#pragma unroll
        for (int bn = 0; bn < 4; ++bn)
#pragma unroll
          for (int kk = 0; kk < 2; ++kk)
            acc[q * 2 + m2][bn] = __builtin_amdgcn_mfma_f32_16x16x32_bf16(
                af[m2][kk], bfv[bn][kk], acc[q * 2 + m2][bn], 0, 0, 0);
      __builtin_amdgcn_s_setprio(0);
      if (q < 3) __builtin_amdgcn_s_barrier();
    }
    const int rem = nt - 1 - t;
    if (rem >= 2)      asm volatile("s_waitcnt vmcnt(4)" ::: "memory");
    else if (rem == 1) asm volatile("s_waitcnt vmcnt(0)" ::: "memory");
    __builtin_amdgcn_s_barrier();
  }
}

__device__ __forceinline__ void zero_acc4(vf4 (&acc)[4][4]) {
  const vf4 z = {0.f, 0.f, 0.f, 0.f};
#pragma unroll
  for (int mt = 0; mt < 4; ++mt)
#pragma unroll
    for (int nt = 0; nt < 4; ++nt) acc[mt][nt] = z;
}
__device__ __forceinline__ void zero_acc8(vf4 (&acc)[8][4]) {
  const vf4 z = {0.f, 0.f, 0.f, 0.f};
#pragma unroll
  for (int mt = 0; mt < 8; ++mt)
#pragma unroll
    for (int nt = 0; nt < 4; ++nt) acc[mt][nt] = z;
}

// ---------------------------------------------------------------------------
// Pack kernels
// ---------------------------------------------------------------------------
__global__ __launch_bounds__(256) void pack_x(const float* __restrict__ x,
                                              bf16_t* __restrict__ Xb) {
  const size_t idx = (size_t)blockIdx.x * 256 + threadIdx.x;
  const float4 v = ((const float4*)x)[idx];
  vbf4 o;
  o[0] = (bf16_t)v.x; o[1] = (bf16_t)v.y; o[2] = (bf16_t)v.z; o[3] = (bf16_t)v.w;
  ((vbf4*)Xb)[idx] = o;
}

// LDS-tiled transpose: 64x64 tile, coalesced read and write
__global__ __launch_bounds__(256) void pack_w(const float* __restrict__ wq,
                                              const float* __restrict__ wk,
                                              const float* __restrict__ wv,
                                              const float* __restrict__ wo,
                                              bf16_t* __restrict__ Wq, bf16_t* __restrict__ Wk,
                                              bf16_t* __restrict__ Wv, bf16_t* __restrict__ Wo,
                                              float scaling) {
  __shared__ float t[64][65];
  const int wid = blockIdx.y;
  const float* src = (wid == 0) ? wq : (wid == 1) ? wk : (wid == 2) ? wv : wo;
  bf16_t* dst = (wid == 0) ? Wq : (wid == 1) ? Wk : (wid == 2) ? Wv : Wo;
  const float sc = (wid == 0) ? scaling : 1.0f;
  const int kt = (blockIdx.x / 12) * 64;
  const int nt = (blockIdx.x % 12) * 64;
  const int tx = threadIdx.x & 63;
  const int ty = threadIdx.x >> 6;
#pragma unroll
  for (int p = 0; p < 16; ++p) {
    const int k = ty + p * 4;
    t[tx][k] = src[(size_t)(kt + k) * 768 + nt + tx] * sc;
  }
  __syncthreads();
#pragma unroll
  for (int p = 0; p < 16; ++p) {
    const int n = ty + p * 4;
    dst[(size_t)(nt + n) * 768 + kt + tx] = (bf16_t)t[n][tx];
  }
}

// ---------------------------------------------------------------------------
// QKV projection: 256x256 tiles, pipelined. bx -> (m_idx, n_idx, z); 9 blocks
// sharing an A-tile adjacent. z=0 Q head-major, z=1 K head-major, z=2 V transp.
// ---------------------------------------------------------------------------
__global__ __launch_bounds__(512, 2) void qkv_gemm(const bf16_t* __restrict__ Xb,
                                                   const bf16_t* __restrict__ Wq,
                                                   const bf16_t* __restrict__ Wk,
                                                   const bf16_t* __restrict__ Wv,
                                                   const float* __restrict__ bq,
                                                   const float* __restrict__ bk,
                                                   const float* __restrict__ bv,
                                                   bf16_t* __restrict__ Qh,
                                                   bf16_t* __restrict__ Kh,
                                                   bf16_t* __restrict__ Vt,
                                                   float scaling) {
  __shared__ __align__(16) bf16_t As[2][256 * 64];
  __shared__ __align__(16) bf16_t Bs[2][256 * 64];
  const int bx = blockIdx.x;
  const int m_idx = bx / 9;
  const int rem = bx - m_idx * 9;
  const int n_idx = rem / 3;
  const int z = rem - n_idx * 3;
  const int m0 = m_idx * 256;
  const int n0 = n_idx * 256;
  const bf16_t* W = (z == 0) ? Wq : (z == 1) ? Wk : Wv;
  vf4 acc[8][4];
  zero_acc8(acc);
  gemm_pipe256(Xb, 768, m0, W, 768, n0, 12, As, Bs, acc);

  const int lane = threadIdx.x & 63;
  const int wave = threadIdx.x >> 6;
  const int aRow0 = (wave >> 2) * 128;
  const int bRow0 = (wave & 3) * 64;
  const int col = lane & 15;
  const int rq = (lane >> 4) * 4;
  const float* bias = (z == 0) ? bq : (z == 1) ? bk : bv;
  const float bsc = (z == 0) ? scaling : 1.0f;

  if (z < 2) {
    bf16_t* O = (z == 0) ? Qh : Kh;
#pragma unroll
    for (int mt = 0; mt < 8; ++mt) {
#pragma unroll
      for (int nt = 0; nt < 4; ++nt) {
        const int n = n0 + bRow0 + nt * 16 + col;
        const int h = n >> 6, d = n & 63;
        const float bb = bias[n] * bsc;
#pragma unroll
        for (int i = 0; i < 4; ++i) {
          const int m = m0 + aRow0 + mt * 16 + rq + i;
          const int r = m >> 8, c = m & 255;
          O[(size_t)(h * 256 + c) * 8192 + (r << 6) + d] = (bf16_t)(acc[mt][nt][i] + bb);
        }
      }
    }
  } else {
#pragma unroll
    for (int mt = 0; mt < 8; ++mt) {
      const int mb = m0 + aRow0 + mt * 16 + rq;
      const int r = mb >> 8, c = mb & 255;
#pragma unroll
      for (int nt = 0; nt < 4; ++nt) {
        const int n = n0 + bRow0 + nt * 16 + col;
        const int h = n >> 6, d = n & 63;
        const float bb = bias[n];
        vbf4 pk;
#pragma unroll
        for (int i = 0; i < 4; ++i) pk[i] = (bf16_t)(acc[mt][nt][i] + bb);
        *(vbf4*)&Vt[(size_t)h * 2097152 + ((size_t)((r << 6) + d)) * 256 + c] = pk;
      }
    }
  }
}

// ---------------------------------------------------------------------------
// Logits: split-K x16, NON-ATOMIC partials Lp[kseg][h][i][j]
// grid (2, 2, 192): z = h*16 + kseg
// ---------------------------------------------------------------------------
__global__ __launch_bounds__(256) void logits_gemm(const bf16_t* __restrict__ Qh,
                                                   const bf16_t* __restrict__ Kh,
                                                   float* __restrict__ Lp) {
  __shared__ __align__(16) bf16_t As[128 * 64];
  __shared__ __align__(16) bf16_t Bs[128 * 64];
  const int n0 = blockIdx.x * 128;
  const int m0 = blockIdx.y * 128;
  const int h = blockIdx.z >> 4;
  const int kseg = blockIdx.z & 15;
  const bf16_t* A = Qh + (size_t)h * (256 * 8192);
  const bf16_t* B = Kh + (size_t)h * (256 * 8192);
  vf4 acc[4][4];
  zero_acc4(acc);
  gemm_mainloop128(A, 8192, m0, B, 8192, n0, kseg * 512, kseg * 512 + 512, As, Bs, acc);

  const int lane = threadIdx.x & 63;
  const int wave = threadIdx.x >> 6;
  const int wm0 = (wave >> 1) * 64;
  const int wn0 = (wave & 1) * 64;
  const int col = lane & 15;
  const int rq = (lane >> 4) * 4;
  float* Lph = Lp + ((size_t)(kseg * 12 + h)) * 65536;
#pragma unroll
  for (int mt = 0; mt < 4; ++mt)
#pragma unroll
    for (int nt = 0; nt < 4; ++nt) {
      const int n = n0 + wn0 + nt * 16 + col;
#pragma unroll
      for (int i = 0; i < 4; ++i) {
        const int m = m0 + wm0 + mt * 16 + rq + i;
        Lph[(size_t)m * 256 + n] = acc[mt][nt][i];
      }
    }
}

// ---------------------------------------------------------------------------
// Softmax: reduce 16 partials + softmax over j. One wave per row (3072 rows).
// ---------------------------------------------------------------------------
__global__ __launch_bounds__(256) void softmax_k(const float* __restrict__ Lp,
                                                 bf16_t* __restrict__ P) {
  const int row = blockIdx.x * 4 + (threadIdx.x >> 6);  // h*256 + i
  const int lane = threadIdx.x & 63;
  float a = 0.f, b = 0.f, c = 0.f, d = 0.f;
#pragma unroll
  for (int ks = 0; ks < 16; ++ks) {
    const float4 v4 = ((const float4*)(Lp + (size_t)ks * 786432 + (size_t)row * 256))[lane];
    a += v4.x; b += v4.y; c += v4.z; d += v4.w;
  }
  float mx = fmaxf(fmaxf(a, b), fmaxf(c, d));
#pragma unroll
  for (int off = 32; off; off >>= 1) mx = fmaxf(mx, __shfl_xor(mx, off));
  a = expf(a - mx); b = expf(b - mx); c = expf(c - mx); d = expf(d - mx);
  float s = a + b + c + d;
#pragma unroll
  for (int off = 32; off; off >>= 1) s += __shfl_xor(s, off);
  const float inv = 1.0f / s;
  vbf4 o;
  o[0] = (bf16_t)(a * inv); o[1] = (bf16_t)(b * inv);
  o[2] = (bf16_t)(c * inv); o[3] = (bf16_t)(d * inv);
  ((vbf4*)(P + (size_t)row * 256))[lane] = o;
}

// ---------------------------------------------------------------------------
// Context: 256x256 pipelined tile (M=256 exactly, K=256 -> nt=4).
// grid (32, 12). Token-major output.
// ---------------------------------------------------------------------------
__global__ __launch_bounds__(512, 2) void ctx_gemm(const bf16_t* __restrict__ P,
                                                   const bf16_t* __restrict__ Vt,
                                                   bf16_t* __restrict__ CtxTok) {
  __shared__ __align__(16) bf16_t As[2][256 * 64];
  __shared__ __align__(16) bf16_t Bs[2][256 * 64];
  const int n0 = blockIdx.x * 256;
  const int h = blockIdx.y;
  const bf16_t* A = P + (size_t)h * 65536;
  const bf16_t* B = Vt + (size_t)h * 2097152;
  vf4 acc[8][4];
  zero_acc8(acc);
  gemm_pipe256(A, 256, 0, B, 256, n0, 4, As, Bs, acc);

  const int lane = threadIdx.x & 63;
  const int wave = threadIdx.x >> 6;
  const int aRow0 = (wave >> 2) * 128;
  const int bRow0 = (wave & 3) * 64;
  const int col = lane & 15;
  const int rq = (lane >> 4) * 4;
#pragma unroll
  for (int mt = 0; mt < 8; ++mt)
#pragma unroll
    for (int nt = 0; nt < 4; ++nt) {
      const int n = n0 + bRow0 + nt * 16 + col;
      const int r = n >> 6, d = n & 63;
#pragma unroll
      for (int i = 0; i < 4; ++i) {
        const int m = aRow0 + mt * 16 + rq + i;
        CtxTok[(size_t)((r << 8) + m) * 768 + (h << 6) + d] = (bf16_t)acc[mt][nt][i];
      }
    }
}

// ---------------------------------------------------------------------------
// Output projection: 256x256 pipelined tiles, bx -> (m_idx, n_idx)
// ---------------------------------------------------------------------------
__global__ __launch_bounds__(512, 2) void out_gemm(const bf16_t* __restrict__ Ctx,
                                                   const bf16_t* __restrict__ Wo,
                                                   const float* __restrict__ bo,
                                                   float* __restrict__ Out) {
  __shared__ __align__(16) bf16_t As[2][256 * 64];
  __shared__ __align__(16) bf16_t Bs[2][256 * 64];
  const int bx = blockIdx.x;
  const int m_idx = bx / 3;
  const int n_idx = bx - m_idx * 3;
  const int m0 = m_idx * 256;
  const int n0 = n_idx * 256;
  vf4 acc[8][4];
  zero_acc8(acc);
  gemm_pipe256(Ctx, 768, m0, Wo, 768, n0, 12, As, Bs, acc);

  const int lane = threadIdx.x & 63;
  const int wave = threadIdx.x >> 6;
  const int aRow0 = (wave >> 2) * 128;
  const int bRow0 = (wave & 3) * 64;
  const int col = lane & 15;
  const int rq = (lane >> 4) * 4;
#pragma unroll
  for (int mt = 0; mt < 8; ++mt)
#pragma unroll
    for (int nt = 0; nt < 4; ++nt) {
      const int n = n0 + bRow0 + nt * 16 + col;
      const float bb = bo[n];
#pragma unroll
      for (int i = 0; i < 4; ++i) {
        const int m = m0 + aRow0 + mt * 16 + rq + i;
        Out[(size_t)m * 768 + n] = acc[mt][nt][i] + bb;
      }
    }
}

// ---------------------------------------------------------------------------
extern "C" void kernel_launch(void* const* d_in, const int* in_sizes, int n_in,
                              void* d_out, int out_size, void* d_ws, size_t ws_size,
                              hipStream_t stream) {
  const float* x  = (const float*)d_in[0];
  const float* wq = (const float*)d_in[1];
  const float* bq = (const float*)d_in[2];
  const float* wk = (const float*)d_in[3];
  const float* bk = (const float*)d_in[4];
  const float* wv = (const float*)d_in[5];
  const float* bv = (const float*)d_in[6];
  const float* wo = (const float*)d_in[7];
  const float* bo = (const float*)d_in[8];
  float* out = (float*)d_out;

  char* ws = (char*)d_ws;
  bf16_t* Xb  = (bf16_t*)(ws + OFF_XB);
  float*  Lp  = (float*)(ws + OFF_XB);    // alias: Xb dead after QKV
  bf16_t* Ctx = (bf16_t*)(ws + OFF_XB);   // alias: Lp dead after softmax
  bf16_t* Qh  = (bf16_t*)(ws + OFF_Q);
  bf16_t* Kh  = (bf16_t*)(ws + OFF_K);
  bf16_t* Vt  = (bf16_t*)(ws + OFF_VT);
  bf16_t* P   = (bf16_t*)(ws + OFF_P);
  bf16_t* Wq  = (bf16_t*)(ws + OFF_WQ);
  bf16_t* Wk  = (bf16_t*)(ws + OFF_WK);
  bf16_t* Wv  = (bf16_t*)(ws + OFF_WV);
  bf16_t* Wo  = (bf16_t*)(ws + OFF_WO);

  const float scaling = 0.125f / sqrtf(128.0f);  // D^-0.5 / sqrt(R)

  pack_x<<<24576, 256, 0, stream>>>(x, Xb);
  pack_w<<<dim3(144, 4), 256, 0, stream>>>(wq, wk, wv, wo, Wq, Wk, Wv, Wo, scaling);
  qkv_gemm<<<1152, 512, 0, stream>>>(Xb, Wq, Wk, Wv, bq, bk, bv, Qh, Kh, Vt, scaling);
  logits_gemm<<<dim3(2, 2, 192), 256, 0, stream>>>(Qh, Kh, Lp);
  softmax_k<<<768, 256, 0, stream>>>(Lp, P);
  ctx_gemm<<<dim3(32, 12), 512, 0, stream>>>(P, Vt, Ctx);
  out_gemm<<<384, 512, 0, stream>>>(Ctx, Wo, bo, out);

  (void)in_sizes; (void)n_in; (void)out_size; (void)ws_size;
}

// Round 3
// 449.284 us; speedup vs baseline: 1.0765x; 1.0765x over previous
//
#include <hip/hip_runtime.h>
#include <hip/hip_bf16.h>
#include <math.h>

typedef __bf16 bf16_t;
typedef __bf16 vbf4 __attribute__((ext_vector_type(4)));
typedef __bf16 vbf8 __attribute__((ext_vector_type(8)));
typedef float  vf4  __attribute__((ext_vector_type(4)));

// Workspace layout (bytes). Total = 207,618,048 (~198 MB)
// OFF_XB region is triple-used (stream-ordered): Xb -> Lp partials -> CtxTok
#define OFF_XB   0ull                 // Xb bf16 [32768][768] = 50331648
                                      //  = Lp f32 [16][12][256][256] (logits partials)
                                      //  = CtxTok bf16 [32768][768]
#define OFF_Q    50331648ull          // Qh bf16 [12][256][8192]
#define OFF_K    100663296ull         // Kh bf16 [12][256][8192]
#define OFF_VT   150994944ull         // Vt bf16 [12][8192][256]
#define OFF_P    201326592ull         // P  bf16 [12][256][256]
#define OFF_WQ   202899456ull         // WqT bf16 [768][768] (pre-scaled)
#define OFF_WK   204079104ull
#define OFF_WV   205258752ull
#define OFF_WO   206438400ull

// XCD-aware block swizzle: hardware round-robins blockIdx across the 8 XCDs
// (each with a private, non-coherent L2). Map hw bid -> logical id so that
// logical ids [xcd*per_xcd, (xcd+1)*per_xcd) all land on one XCD; callers
// order logical ids so blocks sharing an operand panel are consecutive.
// Requires gridDim.x == 8 * per_xcd (all our grids satisfy this exactly).
__device__ __forceinline__ int xcd_swizzle(int bid, int per_xcd) {
  return (bid & 7) * per_xcd + (bid >> 3);
}

// ---------------------------------------------------------------------------
// Staging: ROWS x 64 bf16 tile via global_load_lds width=16, XOR-swizzled:
// LDS[r][chunk j] holds global chunk (j ^ (r&7)).
// ---------------------------------------------------------------------------
template <int ROWS>
__device__ __forceinline__ void stage_tile(const bf16_t* __restrict__ g,
                                           int ld, int row0, int k0,
                                           bf16_t* lds, int tid) {
  const int wave = tid >> 6;
  const int lane = tid & 63;
  const int js = (lane & 7) ^ (lane >> 3);
#pragma unroll
  for (int cc = 0; cc < ROWS / 32; ++cc) {
    const int chunk = cc * 4 + wave;
    const int row = chunk * 8 + (lane >> 3);
    const bf16_t* gp = g + (size_t)(row0 + row) * ld + k0 + js * 8;
    bf16_t* lp = lds + chunk * 512 + lane * 8;
    __builtin_amdgcn_global_load_lds(
        (const __attribute__((address_space(1))) void*)gp,
        (__attribute__((address_space(3))) void*)lp, 16, 0, 0);
  }
}

__device__ __forceinline__ vbf8 lds_frag(const bf16_t* s, int rr, int ko) {
  const int c = (ko >> 3) ^ (rr & 7);
  return *(const vbf8*)&s[rr * 64 + (c << 3)];
}

// ---------------------------------------------------------------------------
// 128x128 mainloop (4 waves, 4x4 tiles/wave) — used by logits
// ---------------------------------------------------------------------------
__device__ __forceinline__ void gemm_mainloop128(const bf16_t* __restrict__ A, int lda, int m0,
                                                 const bf16_t* __restrict__ Bt, int ldb, int n0,
                                                 int kbeg, int kend,
                                                 bf16_t* As, bf16_t* Bs,
                                                 vf4 (&acc)[4][4]) {
  const int tid = threadIdx.x;
  const int lane = tid & 63;
  const int wave = tid >> 6;
  const int wm0 = (wave >> 1) * 64;
  const int wn0 = (wave & 1) * 64;
  const int fm = lane & 15;
  const int fk = (lane >> 4) * 8;
  for (int k0 = kbeg; k0 < kend; k0 += 64) {
    stage_tile<128>(A, lda, m0, k0, As, tid);
    stage_tile<128>(Bt, ldb, n0, k0, Bs, tid);
    __syncthreads();
#pragma unroll
    for (int kk = 0; kk < 64; kk += 32) {
      vbf8 af[4], bfv[4];
#pragma unroll
      for (int mt = 0; mt < 4; ++mt) af[mt] = lds_frag(As, wm0 + mt * 16 + fm, kk + fk);
#pragma unroll
      for (int nt = 0; nt < 4; ++nt) bfv[nt] = lds_frag(Bs, wn0 + nt * 16 + fm, kk + fk);
#pragma unroll
      for (int mt = 0; mt < 4; ++mt)
#pragma unroll
        for (int nt = 0; nt < 4; ++nt)
          acc[mt][nt] = __builtin_amdgcn_mfma_f32_16x16x32_bf16(af[mt], bfv[nt],
                                                                acc[mt][nt], 0, 0, 0);
    }
    __syncthreads();
  }
}

// ---------------------------------------------------------------------------
// 256x128 mainloop (4 waves, 8x4 tiles/wave: two 64-row quadrants per wave).
// Doubles MFMA per staged byte / per barrier vs 128x128.
// ---------------------------------------------------------------------------
__device__ __forceinline__ void gemm_mainloop256(const bf16_t* __restrict__ A, int lda, int m0,
                                                 const bf16_t* __restrict__ Bt, int ldb, int n0,
                                                 int kbeg, int kend,
                                                 bf16_t* As, bf16_t* Bs,
                                                 vf4 (&acc)[8][4]) {
  const int tid = threadIdx.x;
  const int lane = tid & 63;
  const int wave = tid >> 6;
  const int wq0 = (wave >> 1) * 64;
  const int wn0 = (wave & 1) * 64;
  const int fm = lane & 15;
  const int fk = (lane >> 4) * 8;
  for (int k0 = kbeg; k0 < kend; k0 += 64) {
    stage_tile<256>(A, lda, m0, k0, As, tid);
    stage_tile<128>(Bt, ldb, n0, k0, Bs, tid);
    __syncthreads();
#pragma unroll
    for (int kk = 0; kk < 64; kk += 32) {
      vbf8 af[8], bfv[4];
#pragma unroll
      for (int mt = 0; mt < 8; ++mt) {
        const int rr = ((mt & 4) << 5) + wq0 + (mt & 3) * 16 + fm;  // +128 for mt>=4
        af[mt] = lds_frag(As, rr, kk + fk);
      }
#pragma unroll
      for (int nt = 0; nt < 4; ++nt) bfv[nt] = lds_frag(Bs, wn0 + nt * 16 + fm, kk + fk);
#pragma unroll
      for (int mt = 0; mt < 8; ++mt)
#pragma unroll
        for (int nt = 0; nt < 4; ++nt)
          acc[mt][nt] = __builtin_amdgcn_mfma_f32_16x16x32_bf16(af[mt], bfv[nt],
                                                                acc[mt][nt], 0, 0, 0);
    }
    __syncthreads();
  }
}

__device__ __forceinline__ void zero_acc4(vf4 (&acc)[4][4]) {
  const vf4 z = {0.f, 0.f, 0.f, 0.f};
#pragma unroll
  for (int mt = 0; mt < 4; ++mt)
#pragma unroll
    for (int nt = 0; nt < 4; ++nt) acc[mt][nt] = z;
}
__device__ __forceinline__ void zero_acc8(vf4 (&acc)[8][4]) {
  const vf4 z = {0.f, 0.f, 0.f, 0.f};
#pragma unroll
  for (int mt = 0; mt < 8; ++mt)
#pragma unroll
    for (int nt = 0; nt < 4; ++nt) acc[mt][nt] = z;
}

// ---------------------------------------------------------------------------
// Pack kernels
// ---------------------------------------------------------------------------
__global__ __launch_bounds__(256) void pack_x(const float* __restrict__ x,
                                              bf16_t* __restrict__ Xb) {
  const size_t idx = (size_t)blockIdx.x * 256 + threadIdx.x;
  const float4 v = ((const float4*)x)[idx];
  vbf4 o;
  o[0] = (bf16_t)v.x; o[1] = (bf16_t)v.y; o[2] = (bf16_t)v.z; o[3] = (bf16_t)v.w;
  ((vbf4*)Xb)[idx] = o;
}

// LDS-tiled transpose: 64x64 tile, coalesced read and write
__global__ __launch_bounds__(256) void pack_w(const float* __restrict__ wq,
                                              const float* __restrict__ wk,
                                              const float* __restrict__ wv,
                                              const float* __restrict__ wo,
                                              bf16_t* __restrict__ Wq, bf16_t* __restrict__ Wk,
                                              bf16_t* __restrict__ Wv, bf16_t* __restrict__ Wo,
                                              float scaling) {
  __shared__ float t[64][65];
  const int wid = blockIdx.y;
  const float* src = (wid == 0) ? wq : (wid == 1) ? wk : (wid == 2) ? wv : wo;
  bf16_t* dst = (wid == 0) ? Wq : (wid == 1) ? Wk : (wid == 2) ? Wv : Wo;
  const float sc = (wid == 0) ? scaling : 1.0f;
  const int kt = (blockIdx.x / 12) * 64;
  const int nt = (blockIdx.x % 12) * 64;
  const int tx = threadIdx.x & 63;
  const int ty = threadIdx.x >> 6;
#pragma unroll
  for (int p = 0; p < 16; ++p) {
    const int k = ty + p * 4;
    t[tx][k] = src[(size_t)(kt + k) * 768 + nt + tx] * sc;
  }
  __syncthreads();
#pragma unroll
  for (int p = 0; p < 16; ++p) {
    const int n = ty + p * 4;
    dst[(size_t)(nt + n) * 768 + kt + tx] = (bf16_t)t[n][tx];
  }
}

// ---------------------------------------------------------------------------
// QKV projection: 256x128 tiles. Logical id -> (m_idx, n_idx, z); the 18
// blocks sharing an A-tile are consecutive logical ids, and the XCD swizzle
// pins each group of 18 to one XCD (2304 = 8 XCDs x 16 groups x 18).
// z=0 Q head-major, z=1 K head-major, z=2 V transposed.
// ---------------------------------------------------------------------------
__global__ __launch_bounds__(256, 2) void qkv_gemm(const bf16_t* __restrict__ Xb,
                                                   const bf16_t* __restrict__ Wq,
                                                   const bf16_t* __restrict__ Wk,
                                                   const bf16_t* __restrict__ Wv,
                                                   const float* __restrict__ bq,
                                                   const float* __restrict__ bk,
                                                   const float* __restrict__ bv,
                                                   bf16_t* __restrict__ Qh,
                                                   bf16_t* __restrict__ Kh,
                                                   bf16_t* __restrict__ Vt,
                                                   float scaling) {
  __shared__ __align__(16) bf16_t As[256 * 64];
  __shared__ __align__(16) bf16_t Bs[128 * 64];
  const int bx = xcd_swizzle(blockIdx.x, 288);
  const int m_idx = bx / 18;
  const int rem = bx - m_idx * 18;
  const int n_idx = rem / 3;
  const int z = rem - n_idx * 3;
  const int m0 = m_idx * 256;
  const int n0 = n_idx * 128;
  const bf16_t* W = (z == 0) ? Wq : (z == 1) ? Wk : Wv;
  vf4 acc[8][4];
  zero_acc8(acc);
  gemm_mainloop256(Xb, 768, m0, W, 768, n0, 0, 768, As, Bs, acc);

  const int lane = threadIdx.x & 63;
  const int wave = threadIdx.x >> 6;
  const int wq0 = (wave >> 1) * 64;
  const int wn0 = (wave & 1) * 64;
  const int col = lane & 15;
  const int rq = (lane >> 4) * 4;
  const float* bias = (z == 0) ? bq : (z == 1) ? bk : bv;
  const float bsc = (z == 0) ? scaling : 1.0f;

  if (z < 2) {
    bf16_t* O = (z == 0) ? Qh : Kh;
#pragma unroll
    for (int mt = 0; mt < 8; ++mt) {
#pragma unroll
      for (int nt = 0; nt < 4; ++nt) {
        const int n = n0 + wn0 + nt * 16 + col;
        const int h = n >> 6, d = n & 63;
        const float bb = bias[n] * bsc;
#pragma unroll
        for (int i = 0; i < 4; ++i) {
          const int m = m0 + ((mt & 4) << 5) + wq0 + (mt & 3) * 16 + rq + i;
          const int r = m >> 8, c = m & 255;
          O[(size_t)(h * 256 + c) * 8192 + (r << 6) + d] = (bf16_t)(acc[mt][nt][i] + bb);
        }
      }
    }
  } else {
#pragma unroll
    for (int mt = 0; mt < 8; ++mt) {
      const int mb = m0 + ((mt & 4) << 5) + wq0 + (mt & 3) * 16 + rq;
      const int r = mb >> 8, c = mb & 255;
#pragma unroll
      for (int nt = 0; nt < 4; ++nt) {
        const int n = n0 + wn0 + nt * 16 + col;
        const int h = n >> 6, d = n & 63;
        const float bb = bias[n];
        vbf4 pk;
#pragma unroll
        for (int i = 0; i < 4; ++i) pk[i] = (bf16_t)(acc[mt][nt][i] + bb);
        *(vbf4*)&Vt[(size_t)h * 2097152 + ((size_t)((r << 6) + d)) * 256 + c] = pk;
      }
    }
  }
}

// ---------------------------------------------------------------------------
// Logits: split-K x16, NON-ATOMIC partials Lp[kseg][h][i][j]
// 1-D grid 768; logical id -> (z, m, n) with the 4 blocks sharing a (h,kseg)
// Q/K panel consecutive; swizzle pins each per-XCD run of 96 (=24 z-groups).
// ---------------------------------------------------------------------------
__global__ __launch_bounds__(256) void logits_gemm(const bf16_t* __restrict__ Qh,
                                                   const bf16_t* __restrict__ Kh,
                                                   float* __restrict__ Lp) {
  __shared__ __align__(16) bf16_t As[128 * 64];
  __shared__ __align__(16) bf16_t Bs[128 * 64];
  const int bx = xcd_swizzle(blockIdx.x, 96);
  const int z = bx >> 2;            // h*16 + kseg
  const int h = z >> 4;
  const int kseg = z & 15;
  const int m0 = ((bx >> 1) & 1) * 128;
  const int n0 = (bx & 1) * 128;
  const bf16_t* A = Qh + (size_t)h * (256 * 8192);
  const bf16_t* B = Kh + (size_t)h * (256 * 8192);
  vf4 acc[4][4];
  zero_acc4(acc);
  gemm_mainloop128(A, 8192, m0, B, 8192, n0, kseg * 512, kseg * 512 + 512, As, Bs, acc);

  const int lane = threadIdx.x & 63;
  const int wave = threadIdx.x >> 6;
  const int wm0 = (wave >> 1) * 64;
  const int wn0 = (wave & 1) * 64;
  const int col = lane & 15;
  const int rq = (lane >> 4) * 4;
  float* Lph = Lp + ((size_t)(kseg * 12 + h)) * 65536;
#pragma unroll
  for (int mt = 0; mt < 4; ++mt)
#pragma unroll
    for (int nt = 0; nt < 4; ++nt) {
      const int n = n0 + wn0 + nt * 16 + col;
#pragma unroll
      for (int i = 0; i < 4; ++i) {
        const int m = m0 + wm0 + mt * 16 + rq + i;
        Lph[(size_t)m * 256 + n] = acc[mt][nt][i];
      }
    }
}

// ---------------------------------------------------------------------------
// Softmax: reduce 16 partials + softmax over j. One wave per row (3072 rows).
// ---------------------------------------------------------------------------
__global__ __launch_bounds__(256) void softmax_k(const float* __restrict__ Lp,
                                                 bf16_t* __restrict__ P) {
  const int row = blockIdx.x * 4 + (threadIdx.x >> 6);  // h*256 + i
  const int lane = threadIdx.x & 63;
  float a = 0.f, b = 0.f, c = 0.f, d = 0.f;
#pragma unroll
  for (int ks = 0; ks < 16; ++ks) {
    const float4 v4 = ((const float4*)(Lp + (size_t)ks * 786432 + (size_t)row * 256))[lane];
    a += v4.x; b += v4.y; c += v4.z; d += v4.w;
  }
  float mx = fmaxf(fmaxf(a, b), fmaxf(c, d));
#pragma unroll
  for (int off = 32; off; off >>= 1) mx = fmaxf(mx, __shfl_xor(mx, off));
  a = expf(a - mx); b = expf(b - mx); c = expf(c - mx); d = expf(d - mx);
  float s = a + b + c + d;
#pragma unroll
  for (int off = 32; off; off >>= 1) s += __shfl_xor(s, off);
  const float inv = 1.0f / s;
  vbf4 o;
  o[0] = (bf16_t)(a * inv); o[1] = (bf16_t)(b * inv);
  o[2] = (bf16_t)(c * inv); o[3] = (bf16_t)(d * inv);
  ((vbf4*)(P + (size_t)row * 256))[lane] = o;
}

// ---------------------------------------------------------------------------
// Context: 256x128 tile (M=256 exactly). 1-D grid 768 (12 heads x 64 n-tiles);
// logical id -> (h, n) with the 64 blocks sharing a head's Vt consecutive
// (96 logical slots per XCD). Token-major output.
// ---------------------------------------------------------------------------
__global__ __launch_bounds__(256, 2) void ctx_gemm(const bf16_t* __restrict__ P,
                                                   const bf16_t* __restrict__ Vt,
                                                   bf16_t* __restrict__ CtxTok) {
  __shared__ __align__(16) bf16_t As[256 * 64];
  __shared__ __align__(16) bf16_t Bs[128 * 64];
  const int bx = xcd_swizzle(blockIdx.x, 96);
  const int h = bx >> 6;
  const int n0 = (bx & 63) * 128;
  const bf16_t* A = P + (size_t)h * 65536;
  const bf16_t* B = Vt + (size_t)h * 2097152;
  vf4 acc[8][4];
  zero_acc8(acc);
  gemm_mainloop256(A, 256, 0, B, 256, n0, 0, 256, As, Bs, acc);

  const int lane = threadIdx.x & 63;
  const int wave = threadIdx.x >> 6;
  const int wq0 = (wave >> 1) * 64;
  const int wn0 = (wave & 1) * 64;
  const int col = lane & 15;
  const int rq = (lane >> 4) * 4;
#pragma unroll
  for (int mt = 0; mt < 8; ++mt)
#pragma unroll
    for (int nt = 0; nt < 4; ++nt) {
      const int n = n0 + wn0 + nt * 16 + col;
      const int r = n >> 6, d = n & 63;
#pragma unroll
      for (int i = 0; i < 4; ++i) {
        const int m = ((mt & 4) << 5) + wq0 + (mt & 3) * 16 + rq + i;
        CtxTok[(size_t)((r << 8) + m) * 768 + (h << 6) + d] = (bf16_t)acc[mt][nt][i];
      }
    }
}

// ---------------------------------------------------------------------------
// Output projection: 256x128 tiles; logical id -> (m_idx, n_idx), the 6
// blocks sharing an A-tile consecutive (768 = 8 XCDs x 16 groups x 6).
// ---------------------------------------------------------------------------
__global__ __launch_bounds__(256, 2) void out_gemm(const bf16_t* __restrict__ Ctx,
                                                   const bf16_t* __restrict__ Wo,
                                                   const float* __restrict__ bo,
                                                   float* __restrict__ Out) {
  __shared__ __align__(16) bf16_t As[256 * 64];
  __shared__ __align__(16) bf16_t Bs[128 * 64];
  const int bx = xcd_swizzle(blockIdx.x, 96);
  const int m_idx = bx / 6;
  const int n_idx = bx - m_idx * 6;
  const int m0 = m_idx * 256;
  const int n0 = n_idx * 128;
  vf4 acc[8][4];
  zero_acc8(acc);
  gemm_mainloop256(Ctx, 768, m0, Wo, 768, n0, 0, 768, As, Bs, acc);

  const int lane = threadIdx.x & 63;
  const int wave = threadIdx.x >> 6;
  const int wq0 = (wave >> 1) * 64;
  const int wn0 = (wave & 1) * 64;
  const int col = lane & 15;
  const int rq = (lane >> 4) * 4;
#pragma unroll
  for (int mt = 0; mt < 8; ++mt)
#pragma unroll
    for (int nt = 0; nt < 4; ++nt) {
      const int n = n0 + wn0 + nt * 16 + col;
      const float bb = bo[n];
#pragma unroll
      for (int i = 0; i < 4; ++i) {
        const int m = m0 + ((mt & 4) << 5) + wq0 + (mt & 3) * 16 + rq + i;
        Out[(size_t)m * 768 + n] = acc[mt][nt][i] + bb;
      }
    }
}

// ---------------------------------------------------------------------------
extern "C" void kernel_launch(void* const* d_in, const int* in_sizes, int n_in,
                              void* d_out, int out_size, void* d_ws, size_t ws_size,
                              hipStream_t stream) {
  const float* x  = (const float*)d_in[0];
  const float* wq = (const float*)d_in[1];
  const float* bq = (const float*)d_in[2];
  const float* wk = (const float*)d_in[3];
  const float* bk = (const float*)d_in[4];
  const float* wv = (const float*)d_in[5];
  const float* bv = (const float*)d_in[6];
  const float* wo = (const float*)d_in[7];
  const float* bo = (const float*)d_in[8];
  float* out = (float*)d_out;

  char* ws = (char*)d_ws;
  bf16_t* Xb  = (bf16_t*)(ws + OFF_XB);
  float*  Lp  = (float*)(ws + OFF_XB);    // alias: Xb dead after QKV
  bf16_t* Ctx = (bf16_t*)(ws + OFF_XB);   // alias: Lp dead after softmax
  bf16_t* Qh  = (bf16_t*)(ws + OFF_Q);
  bf16_t* Kh  = (bf16_t*)(ws + OFF_K);
  bf16_t* Vt  = (bf16_t*)(ws + OFF_VT);
  bf16_t* P   = (bf16_t*)(ws + OFF_P);
  bf16_t* Wq  = (bf16_t*)(ws + OFF_WQ);
  bf16_t* Wk  = (bf16_t*)(ws + OFF_WK);
  bf16_t* Wv  = (bf16_t*)(ws + OFF_WV);
  bf16_t* Wo  = (bf16_t*)(ws + OFF_WO);

  const float scaling = 0.125f / sqrtf(128.0f);  // D^-0.5 / sqrt(R)

  pack_x<<<24576, 256, 0, stream>>>(x, Xb);
  pack_w<<<dim3(144, 4), 256, 0, stream>>>(wq, wk, wv, wo, Wq, Wk, Wv, Wo, scaling);
  qkv_gemm<<<2304, 256, 0, stream>>>(Xb, Wq, Wk, Wv, bq, bk, bv, Qh, Kh, Vt, scaling);
  logits_gemm<<<768, 256, 0, stream>>>(Qh, Kh, Lp);
  softmax_k<<<768, 256, 0, stream>>>(Lp, P);
  ctx_gemm<<<768, 256, 0, stream>>>(P, Vt, Ctx);
  out_gemm<<<768, 256, 0, stream>>>(Ctx, Wo, bo, out);

  (void)in_sizes; (void)n_in; (void)out_size; (void)ws_size;
}

// Round 4
// 424.792 us; speedup vs baseline: 1.1386x; 1.0577x over previous
//
#include <hip/hip_runtime.h>
#include <hip/hip_bf16.h>
#include <math.h>

typedef __bf16 bf16_t;
typedef __bf16 vbf4 __attribute__((ext_vector_type(4)));
typedef __bf16 vbf8 __attribute__((ext_vector_type(8)));
typedef float  vf4  __attribute__((ext_vector_type(4)));

// Workspace layout (bytes). Total = 207,618,048 (~198 MB)
// OFF_XB region is triple-used (stream-ordered): Xb -> Lp partials -> CtxTok
#define OFF_XB   0ull                 // Xb bf16 [32768][768] = 50331648
                                      //  = Lp f32 [16][12][256][256] (logits partials)
                                      //  = CtxTok bf16 [32768][768]
#define OFF_Q    50331648ull          // Qh bf16 [12][256][8192]
#define OFF_K    100663296ull         // Kh bf16 [12][256][8192]
#define OFF_VT   150994944ull         // Vt bf16 [12][8192][256]
#define OFF_P    201326592ull         // P  bf16 [12][256][256]
#define OFF_WQ   202899456ull         // WqT bf16 [768][768] (pre-scaled)
#define OFF_WK   204079104ull
#define OFF_WV   205258752ull
#define OFF_WO   206438400ull

// XCD-aware block swizzle: hardware round-robins blockIdx across the 8 XCDs
// (each with a private, non-coherent L2). Map hw bid -> logical id so that
// logical ids [xcd*per_xcd, (xcd+1)*per_xcd) all land on one XCD; callers
// order logical ids so blocks sharing an operand panel are consecutive.
// Requires gridDim.x == 8 * per_xcd (all our grids satisfy this exactly).
__device__ __forceinline__ int xcd_swizzle(int bid, int per_xcd) {
  return (bid & 7) * per_xcd + (bid >> 3);
}

// ---------------------------------------------------------------------------
// Staging: ROWS x 64 bf16 tile via global_load_lds width=16, XOR-swizzled:
// LDS[r][chunk j] holds global chunk (j ^ (r&7)).
// ---------------------------------------------------------------------------
template <int ROWS>
__device__ __forceinline__ void stage_tile(const bf16_t* __restrict__ g,
                                           int ld, int row0, int k0,
                                           bf16_t* lds, int tid) {
  const int wave = tid >> 6;
  const int lane = tid & 63;
  const int js = (lane & 7) ^ (lane >> 3);
#pragma unroll
  for (int cc = 0; cc < ROWS / 32; ++cc) {
    const int chunk = cc * 4 + wave;
    const int row = chunk * 8 + (lane >> 3);
    const bf16_t* gp = g + (size_t)(row0 + row) * ld + k0 + js * 8;
    bf16_t* lp = lds + chunk * 512 + lane * 8;
    __builtin_amdgcn_global_load_lds(
        (const __attribute__((address_space(1))) void*)gp,
        (__attribute__((address_space(3))) void*)lp, 16, 0, 0);
  }
}

__device__ __forceinline__ vbf8 lds_frag(const bf16_t* s, int rr, int ko) {
  const int c = (ko >> 3) ^ (rr & 7);
  return *(const vbf8*)&s[rr * 64 + (c << 3)];
}

// ---------------------------------------------------------------------------
// 128x128 mainloop (4 waves, 4x4 tiles/wave). 32 KB LDS, ~154 combined
// VGPR+AGPR -> 3 blocks/CU resident (vs 2 for the old 256x128 shape).
// Tile-space at this structure (learn_hip, ref-checked): 128^2 = 912 TF
// vs 128x256-class = 823 TF.
// ---------------------------------------------------------------------------
__device__ __forceinline__ void gemm_mainloop128(const bf16_t* __restrict__ A, int lda, int m0,
                                                 const bf16_t* __restrict__ Bt, int ldb, int n0,
                                                 int kbeg, int kend,
                                                 bf16_t* As, bf16_t* Bs,
                                                 vf4 (&acc)[4][4]) {
  const int tid = threadIdx.x;
  const int lane = tid & 63;
  const int wave = tid >> 6;
  const int wm0 = (wave >> 1) * 64;
  const int wn0 = (wave & 1) * 64;
  const int fm = lane & 15;
  const int fk = (lane >> 4) * 8;
  for (int k0 = kbeg; k0 < kend; k0 += 64) {
    stage_tile<128>(A, lda, m0, k0, As, tid);
    stage_tile<128>(Bt, ldb, n0, k0, Bs, tid);
    __syncthreads();
#pragma unroll
    for (int kk = 0; kk < 64; kk += 32) {
      vbf8 af[4], bfv[4];
#pragma unroll
      for (int mt = 0; mt < 4; ++mt) af[mt] = lds_frag(As, wm0 + mt * 16 + fm, kk + fk);
#pragma unroll
      for (int nt = 0; nt < 4; ++nt) bfv[nt] = lds_frag(Bs, wn0 + nt * 16 + fm, kk + fk);
#pragma unroll
      for (int mt = 0; mt < 4; ++mt)
#pragma unroll
        for (int nt = 0; nt < 4; ++nt)
          acc[mt][nt] = __builtin_amdgcn_mfma_f32_16x16x32_bf16(af[mt], bfv[nt],
                                                                acc[mt][nt], 0, 0, 0);
    }
    __syncthreads();
  }
}

__device__ __forceinline__ void zero_acc4(vf4 (&acc)[4][4]) {
  const vf4 z = {0.f, 0.f, 0.f, 0.f};
#pragma unroll
  for (int mt = 0; mt < 4; ++mt)
#pragma unroll
    for (int nt = 0; nt < 4; ++nt) acc[mt][nt] = z;
}

// ---------------------------------------------------------------------------
// Pack kernels
// ---------------------------------------------------------------------------
__global__ __launch_bounds__(256) void pack_x(const float* __restrict__ x,
                                              bf16_t* __restrict__ Xb) {
  const size_t idx = (size_t)blockIdx.x * 256 + threadIdx.x;
  const float4 v = ((const float4*)x)[idx];
  vbf4 o;
  o[0] = (bf16_t)v.x; o[1] = (bf16_t)v.y; o[2] = (bf16_t)v.z; o[3] = (bf16_t)v.w;
  ((vbf4*)Xb)[idx] = o;
}

// LDS-tiled transpose: 64x64 tile, coalesced read and write
__global__ __launch_bounds__(256) void pack_w(const float* __restrict__ wq,
                                              const float* __restrict__ wk,
                                              const float* __restrict__ wv,
                                              const float* __restrict__ wo,
                                              bf16_t* __restrict__ Wq, bf16_t* __restrict__ Wk,
                                              bf16_t* __restrict__ Wv, bf16_t* __restrict__ Wo,
                                              float scaling) {
  __shared__ float t[64][65];
  const int wid = blockIdx.y;
  const float* src = (wid == 0) ? wq : (wid == 1) ? wk : (wid == 2) ? wv : wo;
  bf16_t* dst = (wid == 0) ? Wq : (wid == 1) ? Wk : (wid == 2) ? Wv : Wo;
  const float sc = (wid == 0) ? scaling : 1.0f;
  const int kt = (blockIdx.x / 12) * 64;
  const int nt = (blockIdx.x % 12) * 64;
  const int tx = threadIdx.x & 63;
  const int ty = threadIdx.x >> 6;
#pragma unroll
  for (int p = 0; p < 16; ++p) {
    const int k = ty + p * 4;
    t[tx][k] = src[(size_t)(kt + k) * 768 + nt + tx] * sc;
  }
  __syncthreads();
#pragma unroll
  for (int p = 0; p < 16; ++p) {
    const int n = ty + p * 4;
    dst[(size_t)(nt + n) * 768 + kt + tx] = (bf16_t)t[n][tx];
  }
}

// ---------------------------------------------------------------------------
// QKV projection: 128x128 tiles. Logical id -> (m_idx, n_idx, z); the 18
// blocks sharing an A-tile are consecutive logical ids, and the XCD swizzle
// pins each group of 18 to one XCD (4608 = 8 XCDs x 32 groups x 18).
// z=0 Q head-major, z=1 K head-major, z=2 V transposed.
// ---------------------------------------------------------------------------
__global__ __launch_bounds__(256, 3) void qkv_gemm(const bf16_t* __restrict__ Xb,
                                                   const bf16_t* __restrict__ Wq,
                                                   const bf16_t* __restrict__ Wk,
                                                   const bf16_t* __restrict__ Wv,
                                                   const float* __restrict__ bq,
                                                   const float* __restrict__ bk,
                                                   const float* __restrict__ bv,
                                                   bf16_t* __restrict__ Qh,
                                                   bf16_t* __restrict__ Kh,
                                                   bf16_t* __restrict__ Vt,
                                                   float scaling) {
  __shared__ __align__(16) bf16_t As[128 * 64];
  __shared__ __align__(16) bf16_t Bs[128 * 64];
  const int bx = xcd_swizzle(blockIdx.x, 576);
  const int m_idx = bx / 18;
  const int rem = bx - m_idx * 18;
  const int n_idx = rem / 3;
  const int z = rem - n_idx * 3;
  const int m0 = m_idx * 128;
  const int n0 = n_idx * 128;
  const bf16_t* W = (z == 0) ? Wq : (z == 1) ? Wk : Wv;
  vf4 acc[4][4];
  zero_acc4(acc);
  gemm_mainloop128(Xb, 768, m0, W, 768, n0, 0, 768, As, Bs, acc);

  const int lane = threadIdx.x & 63;
  const int wave = threadIdx.x >> 6;
  const int wm0 = (wave >> 1) * 64;
  const int wn0 = (wave & 1) * 64;
  const int col = lane & 15;
  const int rq = (lane >> 4) * 4;
  const float* bias = (z == 0) ? bq : (z == 1) ? bk : bv;
  const float bsc = (z == 0) ? scaling : 1.0f;

  if (z < 2) {
    bf16_t* O = (z == 0) ? Qh : Kh;
#pragma unroll
    for (int mt = 0; mt < 4; ++mt) {
#pragma unroll
      for (int nt = 0; nt < 4; ++nt) {
        const int n = n0 + wn0 + nt * 16 + col;
        const int h = n >> 6, d = n & 63;
        const float bb = bias[n] * bsc;
#pragma unroll
        for (int i = 0; i < 4; ++i) {
          const int m = m0 + wm0 + mt * 16 + rq + i;
          const int r = m >> 8, c = m & 255;
          O[(size_t)(h * 256 + c) * 8192 + (r << 6) + d] = (bf16_t)(acc[mt][nt][i] + bb);
        }
      }
    }
  } else {
#pragma unroll
    for (int mt = 0; mt < 4; ++mt) {
      const int mb = m0 + wm0 + mt * 16 + rq;
      const int r = mb >> 8, c = mb & 255;
#pragma unroll
      for (int nt = 0; nt < 4; ++nt) {
        const int n = n0 + wn0 + nt * 16 + col;
        const int h = n >> 6, d = n & 63;
        const float bb = bias[n];
        vbf4 pk;
#pragma unroll
        for (int i = 0; i < 4; ++i) pk[i] = (bf16_t)(acc[mt][nt][i] + bb);
        *(vbf4*)&Vt[(size_t)h * 2097152 + ((size_t)((r << 6) + d)) * 256 + c] = pk;
      }
    }
  }
}

// ---------------------------------------------------------------------------
// Logits: split-K x16, NON-ATOMIC partials Lp[kseg][h][i][j]
// 1-D grid 768; logical id -> (z, m, n) with the 4 blocks sharing a (h,kseg)
// Q/K panel consecutive; swizzle pins each per-XCD run of 96 (=24 z-groups).
// ---------------------------------------------------------------------------
__global__ __launch_bounds__(256, 3) void logits_gemm(const bf16_t* __restrict__ Qh,
                                                      const bf16_t* __restrict__ Kh,
                                                      float* __restrict__ Lp) {
  __shared__ __align__(16) bf16_t As[128 * 64];
  __shared__ __align__(16) bf16_t Bs[128 * 64];
  const int bx = xcd_swizzle(blockIdx.x, 96);
  const int z = bx >> 2;            // h*16 + kseg
  const int h = z >> 4;
  const int kseg = z & 15;
  const int m0 = ((bx >> 1) & 1) * 128;
  const int n0 = (bx & 1) * 128;
  const bf16_t* A = Qh + (size_t)h * (256 * 8192);
  const bf16_t* B = Kh + (size_t)h * (256 * 8192);
  vf4 acc[4][4];
  zero_acc4(acc);
  gemm_mainloop128(A, 8192, m0, B, 8192, n0, kseg * 512, kseg * 512 + 512, As, Bs, acc);

  const int lane = threadIdx.x & 63;
  const int wave = threadIdx.x >> 6;
  const int wm0 = (wave >> 1) * 64;
  const int wn0 = (wave & 1) * 64;
  const int col = lane & 15;
  const int rq = (lane >> 4) * 4;
  float* Lph = Lp + ((size_t)(kseg * 12 + h)) * 65536;
#pragma unroll
  for (int mt = 0; mt < 4; ++mt)
#pragma unroll
    for (int nt = 0; nt < 4; ++nt) {
      const int n = n0 + wn0 + nt * 16 + col;
#pragma unroll
      for (int i = 0; i < 4; ++i) {
        const int m = m0 + wm0 + mt * 16 + rq + i;
        Lph[(size_t)m * 256 + n] = acc[mt][nt][i];
      }
    }
}

// ---------------------------------------------------------------------------
// Softmax: reduce 16 partials + softmax over j. One wave per row (3072 rows).
// ---------------------------------------------------------------------------
__global__ __launch_bounds__(256) void softmax_k(const float* __restrict__ Lp,
                                                 bf16_t* __restrict__ P) {
  const int row = blockIdx.x * 4 + (threadIdx.x >> 6);  // h*256 + i
  const int lane = threadIdx.x & 63;
  float a = 0.f, b = 0.f, c = 0.f, d = 0.f;
#pragma unroll
  for (int ks = 0; ks < 16; ++ks) {
    const float4 v4 = ((const float4*)(Lp + (size_t)ks * 786432 + (size_t)row * 256))[lane];
    a += v4.x; b += v4.y; c += v4.z; d += v4.w;
  }
  float mx = fmaxf(fmaxf(a, b), fmaxf(c, d));
#pragma unroll
  for (int off = 32; off; off >>= 1) mx = fmaxf(mx, __shfl_xor(mx, off));
  a = expf(a - mx); b = expf(b - mx); c = expf(c - mx); d = expf(d - mx);
  float s = a + b + c + d;
#pragma unroll
  for (int off = 32; off; off >>= 1) s += __shfl_xor(s, off);
  const float inv = 1.0f / s;
  vbf4 o;
  o[0] = (bf16_t)(a * inv); o[1] = (bf16_t)(b * inv);
  o[2] = (bf16_t)(c * inv); o[3] = (bf16_t)(d * inv);
  ((vbf4*)(P + (size_t)row * 256))[lane] = o;
}

// ---------------------------------------------------------------------------
// Context: 128x128 tiles. 1-D grid 1536 (12 heads x 64 n-tiles x 2 m-tiles);
// logical id -> (h, n, m) with blocks sharing a head's Vt consecutive
// (192 logical slots per XCD = 1.5 heads). Token-major output.
// ---------------------------------------------------------------------------
__global__ __launch_bounds__(256, 3) void ctx_gemm(const bf16_t* __restrict__ P,
                                                   const bf16_t* __restrict__ Vt,
                                                   bf16_t* __restrict__ CtxTok) {
  __shared__ __align__(16) bf16_t As[128 * 64];
  __shared__ __align__(16) bf16_t Bs[128 * 64];
  const int bx = xcd_swizzle(blockIdx.x, 192);
  const int h = bx >> 7;
  const int rem = bx & 127;
  const int n0 = (rem >> 1) * 128;
  const int m0 = (rem & 1) * 128;
  const bf16_t* A = P + (size_t)h * 65536;
  const bf16_t* B = Vt + (size_t)h * 2097152;
  vf4 acc[4][4];
  zero_acc4(acc);
  gemm_mainloop128(A, 256, m0, B, 256, n0, 0, 256, As, Bs, acc);

  const int lane = threadIdx.x & 63;
  const int wave = threadIdx.x >> 6;
  const int wm0 = (wave >> 1) * 64;
  const int wn0 = (wave & 1) * 64;
  const int col = lane & 15;
  const int rq = (lane >> 4) * 4;
#pragma unroll
  for (int mt = 0; mt < 4; ++mt)
#pragma unroll
    for (int nt = 0; nt < 4; ++nt) {
      const int n = n0 + wn0 + nt * 16 + col;
      const int r = n >> 6, d = n & 63;
#pragma unroll
      for (int i = 0; i < 4; ++i) {
        const int m = m0 + wm0 + mt * 16 + rq + i;
        CtxTok[(size_t)((r << 8) + m) * 768 + (h << 6) + d] = (bf16_t)acc[mt][nt][i];
      }
    }
}

// ---------------------------------------------------------------------------
// Output projection: 128x128 tiles; logical id -> (m_idx, n_idx), the 6
// blocks sharing an A-tile consecutive (1536 = 8 XCDs x 32 groups x 6).
// ---------------------------------------------------------------------------
__global__ __launch_bounds__(256, 3) void out_gemm(const bf16_t* __restrict__ Ctx,
                                                   const bf16_t* __restrict__ Wo,
                                                   const float* __restrict__ bo,
                                                   float* __restrict__ Out) {
  __shared__ __align__(16) bf16_t As[128 * 64];
  __shared__ __align__(16) bf16_t Bs[128 * 64];
  const int bx = xcd_swizzle(blockIdx.x, 192);
  const int m_idx = bx / 6;
  const int n_idx = bx - m_idx * 6;
  const int m0 = m_idx * 128;
  const int n0 = n_idx * 128;
  vf4 acc[4][4];
  zero_acc4(acc);
  gemm_mainloop128(Ctx, 768, m0, Wo, 768, n0, 0, 768, As, Bs, acc);

  const int lane = threadIdx.x & 63;
  const int wave = threadIdx.x >> 6;
  const int wm0 = (wave >> 1) * 64;
  const int wn0 = (wave & 1) * 64;
  const int col = lane & 15;
  const int rq = (lane >> 4) * 4;
#pragma unroll
  for (int mt = 0; mt < 4; ++mt)
#pragma unroll
    for (int nt = 0; nt < 4; ++nt) {
      const int n = n0 + wn0 + nt * 16 + col;
      const float bb = bo[n];
#pragma unroll
      for (int i = 0; i < 4; ++i) {
        const int m = m0 + wm0 + mt * 16 + rq + i;
        Out[(size_t)m * 768 + n] = acc[mt][nt][i] + bb;
      }
    }
}

// ---------------------------------------------------------------------------
extern "C" void kernel_launch(void* const* d_in, const int* in_sizes, int n_in,
                              void* d_out, int out_size, void* d_ws, size_t ws_size,
                              hipStream_t stream) {
  const float* x  = (const float*)d_in[0];
  const float* wq = (const float*)d_in[1];
  const float* bq = (const float*)d_in[2];
  const float* wk = (const float*)d_in[3];
  const float* bk = (const float*)d_in[4];
  const float* wv = (const float*)d_in[5];
  const float* bv = (const float*)d_in[6];
  const float* wo = (const float*)d_in[7];
  const float* bo = (const float*)d_in[8];
  float* out = (float*)d_out;

  char* ws = (char*)d_ws;
  bf16_t* Xb  = (bf16_t*)(ws + OFF_XB);
  float*  Lp  = (float*)(ws + OFF_XB);    // alias: Xb dead after QKV
  bf16_t* Ctx = (bf16_t*)(ws + OFF_XB);   // alias: Lp dead after softmax
  bf16_t* Qh  = (bf16_t*)(ws + OFF_Q);
  bf16_t* Kh  = (bf16_t*)(ws + OFF_K);
  bf16_t* Vt  = (bf16_t*)(ws + OFF_VT);
  bf16_t* P   = (bf16_t*)(ws + OFF_P);
  bf16_t* Wq  = (bf16_t*)(ws + OFF_WQ);
  bf16_t* Wk  = (bf16_t*)(ws + OFF_WK);
  bf16_t* Wv  = (bf16_t*)(ws + OFF_WV);
  bf16_t* Wo  = (bf16_t*)(ws + OFF_WO);

  const float scaling = 0.125f / sqrtf(128.0f);  // D^-0.5 / sqrt(R)

  pack_x<<<24576, 256, 0, stream>>>(x, Xb);
  pack_w<<<dim3(144, 4), 256, 0, stream>>>(wq, wk, wv, wo, Wq, Wk, Wv, Wo, scaling);
  qkv_gemm<<<4608, 256, 0, stream>>>(Xb, Wq, Wk, Wv, bq, bk, bv, Qh, Kh, Vt, scaling);
  logits_gemm<<<768, 256, 0, stream>>>(Qh, Kh, Lp);
  softmax_k<<<768, 256, 0, stream>>>(Lp, P);
  ctx_gemm<<<1536, 256, 0, stream>>>(P, Vt, Ctx);
  out_gemm<<<1536, 256, 0, stream>>>(Ctx, Wo, bo, out);

  (void)in_sizes; (void)n_in; (void)out_size; (void)ws_size;
}

// Round 7
// 405.567 us; speedup vs baseline: 1.1926x; 1.0474x over previous
//
#include <hip/hip_runtime.h>
#include <hip/hip_bf16.h>
#include <math.h>

typedef __bf16 bf16_t;
typedef __bf16 vbf4 __attribute__((ext_vector_type(4)));
typedef __bf16 vbf8 __attribute__((ext_vector_type(8)));
typedef float  vf4  __attribute__((ext_vector_type(4)));

// Workspace layout (bytes). Total = 207,618,048 (~198 MB)
// OFF_XB region is triple-used (stream-ordered): Xb -> Lp partials -> CtxTok
#define OFF_XB   0ull                 // Xb bf16 [32768][768] = 50331648
                                      //  = Lp f32 [16][12][256][256] (logits partials)
                                      //  = CtxTok bf16 [32768][768]
#define OFF_Q    50331648ull          // Qh bf16 [12][256][8192]
#define OFF_K    100663296ull         // Kh bf16 [12][256][8192]
#define OFF_VT   150994944ull         // Vt bf16 [12][8192][256]
#define OFF_P    201326592ull         // P  bf16 [12][256][256]
#define OFF_WQ   202899456ull         // WqT bf16 [768][768] (pre-scaled)
#define OFF_WK   204079104ull
#define OFF_WV   205258752ull
#define OFF_WO   206438400ull

// XCD-aware block swizzle: hardware round-robins blockIdx across the 8 XCDs
// (each with a private, non-coherent L2). Map hw bid -> logical id so that
// logical ids [xcd*per_xcd, (xcd+1)*per_xcd) all land on one XCD; callers
// order logical ids so blocks sharing an operand panel are consecutive.
// Requires gridDim.x == 8 * per_xcd (all our grids satisfy this exactly).
__device__ __forceinline__ int xcd_swizzle(int bid, int per_xcd) {
  return (bid & 7) * per_xcd + (bid >> 3);
}

// ---------------------------------------------------------------------------
// Staging: ROWS x 64 bf16 tile via global_load_lds width=16, XOR-swizzled:
// LDS[r][chunk j] holds global chunk (j ^ (r&7)).
// ---------------------------------------------------------------------------
template <int ROWS>
__device__ __forceinline__ void stage_tile(const bf16_t* __restrict__ g,
                                           int ld, int row0, int k0,
                                           bf16_t* lds, int tid) {
  const int wave = tid >> 6;
  const int lane = tid & 63;
  const int js = (lane & 7) ^ (lane >> 3);
#pragma unroll
  for (int cc = 0; cc < ROWS / 32; ++cc) {
    const int chunk = cc * 4 + wave;
    const int row = chunk * 8 + (lane >> 3);
    const bf16_t* gp = g + (size_t)(row0 + row) * ld + k0 + js * 8;
    bf16_t* lp = lds + chunk * 512 + lane * 8;
    __builtin_amdgcn_global_load_lds(
        (const __attribute__((address_space(1))) void*)gp,
        (__attribute__((address_space(3))) void*)lp, 16, 0, 0);
  }
}

__device__ __forceinline__ vbf8 lds_frag(const bf16_t* s, int rr, int ko) {
  const int c = (ko >> 3) ^ (rr & 7);
  return *(const vbf8*)&s[rr * 64 + (c << 3)];
}

// ---------------------------------------------------------------------------
// 128x128 mainloop (4 waves, 4x4 tiles/wave). 32 KB LDS, ~154 combined
// VGPR+AGPR -> 3 blocks/CU resident (vs 2 for the old 256x128 shape).
// Tile-space at this structure (learn_hip, ref-checked): 128^2 = 912 TF
// vs 128x256-class = 823 TF. Measured here: qkv 872 TF (R4).
// ---------------------------------------------------------------------------
__device__ __forceinline__ void gemm_mainloop128(const bf16_t* __restrict__ A, int lda, int m0,
                                                 const bf16_t* __restrict__ Bt, int ldb, int n0,
                                                 int kbeg, int kend,
                                                 bf16_t* As, bf16_t* Bs,
                                                 vf4 (&acc)[4][4]) {
  const int tid = threadIdx.x;
  const int lane = tid & 63;
  const int wave = tid >> 6;
  const int wm0 = (wave >> 1) * 64;
  const int wn0 = (wave & 1) * 64;
  const int fm = lane & 15;
  const int fk = (lane >> 4) * 8;
  for (int k0 = kbeg; k0 < kend; k0 += 64) {
    stage_tile<128>(A, lda, m0, k0, As, tid);
    stage_tile<128>(Bt, ldb, n0, k0, Bs, tid);
    __syncthreads();
#pragma unroll
    for (int kk = 0; kk < 64; kk += 32) {
      vbf8 af[4], bfv[4];
#pragma unroll
      for (int mt = 0; mt < 4; ++mt) af[mt] = lds_frag(As, wm0 + mt * 16 + fm, kk + fk);
#pragma unroll
      for (int nt = 0; nt < 4; ++nt) bfv[nt] = lds_frag(Bs, wn0 + nt * 16 + fm, kk + fk);
#pragma unroll
      for (int mt = 0; mt < 4; ++mt)
#pragma unroll
        for (int nt = 0; nt < 4; ++nt)
          acc[mt][nt] = __builtin_amdgcn_mfma_f32_16x16x32_bf16(af[mt], bfv[nt],
                                                                acc[mt][nt], 0, 0, 0);
    }
    __syncthreads();
  }
}

__device__ __forceinline__ void zero_acc4(vf4 (&acc)[4][4]) {
  const vf4 z = {0.f, 0.f, 0.f, 0.f};
#pragma unroll
  for (int mt = 0; mt < 4; ++mt)
#pragma unroll
    for (int nt = 0; nt < 4; ++nt) acc[mt][nt] = z;
}

// ---------------------------------------------------------------------------
// Pack kernels
// ---------------------------------------------------------------------------
__global__ __launch_bounds__(256) void pack_x(const float* __restrict__ x,
                                              bf16_t* __restrict__ Xb) {
  const size_t idx = (size_t)blockIdx.x * 256 + threadIdx.x;
  const float4 v = ((const float4*)x)[idx];
  vbf4 o;
  o[0] = (bf16_t)v.x; o[1] = (bf16_t)v.y; o[2] = (bf16_t)v.z; o[3] = (bf16_t)v.w;
  ((vbf4*)Xb)[idx] = o;
}

// LDS-tiled transpose: 64x64 tile, coalesced read and write
__global__ __launch_bounds__(256) void pack_w(const float* __restrict__ wq,
                                              const float* __restrict__ wk,
                                              const float* __restrict__ wv,
                                              const float* __restrict__ wo,
                                              bf16_t* __restrict__ Wq, bf16_t* __restrict__ Wk,
                                              bf16_t* __restrict__ Wv, bf16_t* __restrict__ Wo,
                                              float scaling) {
  __shared__ float t[64][65];
  const int wid = blockIdx.y;
  const float* src = (wid == 0) ? wq : (wid == 1) ? wk : (wid == 2) ? wv : wo;
  bf16_t* dst = (wid == 0) ? Wq : (wid == 1) ? Wk : (wid == 2) ? Wv : Wo;
  const float sc = (wid == 0) ? scaling : 1.0f;
  const int kt = (blockIdx.x / 12) * 64;
  const int nt = (blockIdx.x % 12) * 64;
  const int tx = threadIdx.x & 63;
  const int ty = threadIdx.x >> 6;
#pragma unroll
  for (int p = 0; p < 16; ++p) {
    const int k = ty + p * 4;
    t[tx][k] = src[(size_t)(kt + k) * 768 + nt + tx] * sc;
  }
  __syncthreads();
#pragma unroll
  for (int p = 0; p < 16; ++p) {
    const int n = ty + p * 4;
    dst[(size_t)(nt + n) * 768 + kt + tx] = (bf16_t)t[n][tx];
  }
}

// ---------------------------------------------------------------------------
// QKV projection: 128x128 tiles. Logical id -> (m_idx, n_idx, z); the 18
// blocks sharing an A-tile are consecutive logical ids, and the XCD swizzle
// pins each group of 18 to one XCD (4608 = 8 XCDs x 32 groups x 18).
// z=0 Q head-major, z=1 K head-major, z=2 V transposed.
// ---------------------------------------------------------------------------
__global__ __launch_bounds__(256, 3) void qkv_gemm(const bf16_t* __restrict__ Xb,
                                                   const bf16_t* __restrict__ Wq,
                                                   const bf16_t* __restrict__ Wk,
                                                   const bf16_t* __restrict__ Wv,
                                                   const float* __restrict__ bq,
                                                   const float* __restrict__ bk,
                                                   const float* __restrict__ bv,
                                                   bf16_t* __restrict__ Qh,
                                                   bf16_t* __restrict__ Kh,
                                                   bf16_t* __restrict__ Vt,
                                                   float scaling) {
  __shared__ __align__(16) bf16_t As[128 * 64];
  __shared__ __align__(16) bf16_t Bs[128 * 64];
  const int bx = xcd_swizzle(blockIdx.x, 576);
  const int m_idx = bx / 18;
  const int rem = bx - m_idx * 18;
  const int n_idx = rem / 3;
  const int z = rem - n_idx * 3;
  const int m0 = m_idx * 128;
  const int n0 = n_idx * 128;
  const bf16_t* W = (z == 0) ? Wq : (z == 1) ? Wk : Wv;
  vf4 acc[4][4];
  zero_acc4(acc);
  gemm_mainloop128(Xb, 768, m0, W, 768, n0, 0, 768, As, Bs, acc);

  const int lane = threadIdx.x & 63;
  const int wave = threadIdx.x >> 6;
  const int wm0 = (wave >> 1) * 64;
  const int wn0 = (wave & 1) * 64;
  const int col = lane & 15;
  const int rq = (lane >> 4) * 4;
  const float* bias = (z == 0) ? bq : (z == 1) ? bk : bv;
  const float bsc = (z == 0) ? scaling : 1.0f;

  if (z < 2) {
    bf16_t* O = (z == 0) ? Qh : Kh;
#pragma unroll
    for (int mt = 0; mt < 4; ++mt) {
#pragma unroll
      for (int nt = 0; nt < 4; ++nt) {
        const int n = n0 + wn0 + nt * 16 + col;
        const int h = n >> 6, d = n & 63;
        const float bb = bias[n] * bsc;
#pragma unroll
        for (int i = 0; i < 4; ++i) {
          const int m = m0 + wm0 + mt * 16 + rq + i;
          const int r = m >> 8, c = m & 255;
          O[(size_t)(h * 256 + c) * 8192 + (r << 6) + d] = (bf16_t)(acc[mt][nt][i] + bb);
        }
      }
    }
  } else {
#pragma unroll
    for (int mt = 0; mt < 4; ++mt) {
      const int mb = m0 + wm0 + mt * 16 + rq;
      const int r = mb >> 8, c = mb & 255;
#pragma unroll
      for (int nt = 0; nt < 4; ++nt) {
        const int n = n0 + wn0 + nt * 16 + col;
        const int h = n >> 6, d = n & 63;
        const float bb = bias[n];
        vbf4 pk;
#pragma unroll
        for (int i = 0; i < 4; ++i) pk[i] = (bf16_t)(acc[mt][nt][i] + bb);
        *(vbf4*)&Vt[(size_t)h * 2097152 + ((size_t)((r << 6) + d)) * 256 + c] = pk;
      }
    }
  }
}

// ---------------------------------------------------------------------------
// Logits: split-K x16, NON-ATOMIC partials Lp[kseg][h][i][j]
// 1-D grid 768; logical id -> (z, m, n) with the 4 blocks sharing a (h,kseg)
// Q/K panel consecutive; swizzle pins each per-XCD run of 96 (=24 z-groups).
// ---------------------------------------------------------------------------
__global__ __launch_bounds__(256, 3) void logits_gemm(const bf16_t* __restrict__ Qh,
                                                      const bf16_t* __restrict__ Kh,
                                                      float* __restrict__ Lp) {
  __shared__ __align__(16) bf16_t As[128 * 64];
  __shared__ __align__(16) bf16_t Bs[128 * 64];
  const int bx = xcd_swizzle(blockIdx.x, 96);
  const int z = bx >> 2;            // h*16 + kseg
  const int h = z >> 4;
  const int kseg = z & 15;
  const int m0 = ((bx >> 1) & 1) * 128;
  const int n0 = (bx & 1) * 128;
  const bf16_t* A = Qh + (size_t)h * (256 * 8192);
  const bf16_t* B = Kh + (size_t)h * (256 * 8192);
  vf4 acc[4][4];
  zero_acc4(acc);
  gemm_mainloop128(A, 8192, m0, B, 8192, n0, kseg * 512, kseg * 512 + 512, As, Bs, acc);

  const int lane = threadIdx.x & 63;
  const int wave = threadIdx.x >> 6;
  const int wm0 = (wave >> 1) * 64;
  const int wn0 = (wave & 1) * 64;
  const int col = lane & 15;
  const int rq = (lane >> 4) * 4;
  float* Lph = Lp + ((size_t)(kseg * 12 + h)) * 65536;
#pragma unroll
  for (int mt = 0; mt < 4; ++mt)
#pragma unroll
    for (int nt = 0; nt < 4; ++nt) {
      const int n = n0 + wn0 + nt * 16 + col;
#pragma unroll
      for (int i = 0; i < 4; ++i) {
        const int m = m0 + wm0 + mt * 16 + rq + i;
        Lph[(size_t)m * 256 + n] = acc[mt][nt][i];
      }
    }
}

// ---------------------------------------------------------------------------
// Softmax: reduce 16 partials + softmax over j. One wave per row (3072 rows).
// ---------------------------------------------------------------------------
__global__ __launch_bounds__(256) void softmax_k(const float* __restrict__ Lp,
                                                 bf16_t* __restrict__ P) {
  const int row = blockIdx.x * 4 + (threadIdx.x >> 6);  // h*256 + i
  const int lane = threadIdx.x & 63;
  float a = 0.f, b = 0.f, c = 0.f, d = 0.f;
#pragma unroll
  for (int ks = 0; ks < 16; ++ks) {
    const float4 v4 = ((const float4*)(Lp + (size_t)ks * 786432 + (size_t)row * 256))[lane];
    a += v4.x; b += v4.y; c += v4.z; d += v4.w;
  }
  float mx = fmaxf(fmaxf(a, b), fmaxf(c, d));
#pragma unroll
  for (int off = 32; off; off >>= 1) mx = fmaxf(mx, __shfl_xor(mx, off));
  a = expf(a - mx); b = expf(b - mx); c = expf(c - mx); d = expf(d - mx);
  float s = a + b + c + d;
#pragma unroll
  for (int off = 32; off; off >>= 1) s += __shfl_xor(s, off);
  const float inv = 1.0f / s;
  vbf4 o;
  o[0] = (bf16_t)(a * inv); o[1] = (bf16_t)(b * inv);
  o[2] = (bf16_t)(c * inv); o[3] = (bf16_t)(d * inv);
  ((vbf4*)(P + (size_t)row * 256))[lane] = o;
}

// ---------------------------------------------------------------------------
// Context: 128x128 tiles. 1-D grid 1536 (12 heads x 64 n-tiles x 2 m-tiles);
// logical id -> (h, n, m) with blocks sharing a head's Vt consecutive
// (192 logical slots per XCD = 1.5 heads). Token-major output.
// ---------------------------------------------------------------------------
__global__ __launch_bounds__(256, 3) void ctx_gemm(const bf16_t* __restrict__ P,
                                                   const bf16_t* __restrict__ Vt,
                                                   bf16_t* __restrict__ CtxTok) {
  __shared__ __align__(16) bf16_t As[128 * 64];
  __shared__ __align__(16) bf16_t Bs[128 * 64];
  const int bx = xcd_swizzle(blockIdx.x, 192);
  const int h = bx >> 7;
  const int rem = bx & 127;
  const int n0 = (rem >> 1) * 128;
  const int m0 = (rem & 1) * 128;
  const bf16_t* A = P + (size_t)h * 65536;
  const bf16_t* B = Vt + (size_t)h * 2097152;
  vf4 acc[4][4];
  zero_acc4(acc);
  gemm_mainloop128(A, 256, m0, B, 256, n0, 0, 256, As, Bs, acc);

  const int lane = threadIdx.x & 63;
  const int wave = threadIdx.x >> 6;
  const int wm0 = (wave >> 1) * 64;
  const int wn0 = (wave & 1) * 64;
  const int col = lane & 15;
  const int rq = (lane >> 4) * 4;
#pragma unroll
  for (int mt = 0; mt < 4; ++mt)
#pragma unroll
    for (int nt = 0; nt < 4; ++nt) {
      const int n = n0 + wn0 + nt * 16 + col;
      const int r = n >> 6, d = n & 63;
#pragma unroll
      for (int i = 0; i < 4; ++i) {
        const int m = m0 + wm0 + mt * 16 + rq + i;
        CtxTok[(size_t)((r << 8) + m) * 768 + (h << 6) + d] = (bf16_t)acc[mt][nt][i];
      }
    }
}

// ---------------------------------------------------------------------------
// Output projection: 128x128 tiles; logical id -> (m_idx, n_idx), the 6
// blocks sharing an A-tile consecutive (1536 = 8 XCDs x 32 groups x 6).
// ---------------------------------------------------------------------------
__global__ __launch_bounds__(256, 3) void out_gemm(const bf16_t* __restrict__ Ctx,
                                                   const bf16_t* __restrict__ Wo,
                                                   const float* __restrict__ bo,
                                                   float* __restrict__ Out) {
  __shared__ __align__(16) bf16_t As[128 * 64];
  __shared__ __align__(16) bf16_t Bs[128 * 64];
  const int bx = xcd_swizzle(blockIdx.x, 192);
  const int m_idx = bx / 6;
  const int n_idx = bx - m_idx * 6;
  const int m0 = m_idx * 128;
  const int n0 = n_idx * 128;
  vf4 acc[4][4];
  zero_acc4(acc);
  gemm_mainloop128(Ctx, 768, m0, Wo, 768, n0, 0, 768, As, Bs, acc);

  const int lane = threadIdx.x & 63;
  const int wave = threadIdx.x >> 6;
  const int wm0 = (wave >> 1) * 64;
  const int wn0 = (wave & 1) * 64;
  const int col = lane & 15;
  const int rq = (lane >> 4) * 4;
#pragma unroll
  for (int mt = 0; mt < 4; ++mt)
#pragma unroll
    for (int nt = 0; nt < 4; ++nt) {
      const int n = n0 + wn0 + nt * 16 + col;
      const float bb = bo[n];
#pragma unroll
      for (int i = 0; i < 4; ++i) {
        const int m = m0 + wm0 + mt * 16 + rq + i;
        Out[(size_t)m * 768 + n] = acc[mt][nt][i] + bb;
      }
    }
}

// ---------------------------------------------------------------------------
extern "C" void kernel_launch(void* const* d_in, const int* in_sizes, int n_in,
                              void* d_out, int out_size, void* d_ws, size_t ws_size,
                              hipStream_t stream) {
  const float* x  = (const float*)d_in[0];
  const float* wq = (const float*)d_in[1];
  const float* bq = (const float*)d_in[2];
  const float* wk = (const float*)d_in[3];
  const float* bk = (const float*)d_in[4];
  const float* wv = (const float*)d_in[5];
  const float* bv = (const float*)d_in[6];
  const float* wo = (const float*)d_in[7];
  const float* bo = (const float*)d_in[8];
  float* out = (float*)d_out;

  char* ws = (char*)d_ws;
  bf16_t* Xb  = (bf16_t*)(ws + OFF_XB);
  float*  Lp  = (float*)(ws + OFF_XB);    // alias: Xb dead after QKV
  bf16_t* Ctx = (bf16_t*)(ws + OFF_XB);   // alias: Lp dead after softmax
  bf16_t* Qh  = (bf16_t*)(ws + OFF_Q);
  bf16_t* Kh  = (bf16_t*)(ws + OFF_K);
  bf16_t* Vt  = (bf16_t*)(ws + OFF_VT);
  bf16_t* P   = (bf16_t*)(ws + OFF_P);
  bf16_t* Wq  = (bf16_t*)(ws + OFF_WQ);
  bf16_t* Wk  = (bf16_t*)(ws + OFF_WK);
  bf16_t* Wv  = (bf16_t*)(ws + OFF_WV);
  bf16_t* Wo  = (bf16_t*)(ws + OFF_WO);

  const float scaling = 0.125f / sqrtf(128.0f);  // D^-0.5 / sqrt(R)

  pack_x<<<24576, 256, 0, stream>>>(x, Xb);
  pack_w<<<dim3(144, 4), 256, 0, stream>>>(wq, wk, wv, wo, Wq, Wk, Wv, Wo, scaling);
  qkv_gemm<<<4608, 256, 0, stream>>>(Xb, Wq, Wk, Wv, bq, bk, bv, Qh, Kh, Vt, scaling);
  logits_gemm<<<768, 256, 0, stream>>>(Qh, Kh, Lp);
  softmax_k<<<768, 256, 0, stream>>>(Lp, P);
  ctx_gemm<<<1536, 256, 0, stream>>>(P, Vt, Ctx);
  out_gemm<<<1536, 256, 0, stream>>>(Ctx, Wo, bo, out);

  (void)in_sizes; (void)n_in; (void)out_size; (void)ws_size;
}